// Round 6
// baseline (212.854 us; speedup 1.0000x reference)
//
#include <hip/hip_runtime.h>
#include <math.h>

// Problem constants (from reference)
#define NH 4
#define HD 64
#define HIDDEN 256
#define BS 32
#define NB 64          // NUM_BLOCKS = MAX_LEN/BS = 2048/32
#define SCALE 0.125f
#define INV_SCALE 8.0f

__device__ __forceinline__ float fast_sigmoid(float x) {
    return 1.0f / (1.0f + __expf(-x));
}
__device__ __forceinline__ float readlane_f(float v, int lane) {
    return __int_as_float(__builtin_amdgcn_readlane(__float_as_int(v), lane));
}

// Kernel 1 (unchanged): block means. K in f64 (selection path f64-exact vs np
// reference), V in f32.
__global__ __launch_bounds__(256) void kcmp_kernel(
    const float* __restrict__ k, const float* __restrict__ v,
    const int* __restrict__ x_offsets,
    double* __restrict__ k_cmp, float* __restrict__ v_cmp2) {
    int bb  = blockIdx.x;          // b*NB + blk
    int b   = bb >> 6;
    int blk = bb & 63;
    int tid = threadIdx.x;         // column: h = tid>>6, d = tid&63
    int s0   = x_offsets[b];
    int len  = x_offsets[b + 1] - s0;
    int nblk = len >> 5;
    int h = tid >> 6, d = tid & 63;
    if (blockIdx.y == 0) {
        double acc = 0.0;
        if (blk < nblk) {
            const float* kp = k + (size_t)(s0 + blk * BS) * HIDDEN + tid;
            #pragma unroll
            for (int i = 0; i < BS; ++i) acc += (double)kp[i * HIDDEN];
            acc *= (1.0 / BS);
        }
        k_cmp[((size_t)(b * NH + h) * 64 + blk) * 64 + d] = acc;
    } else {
        float acc = 0.f;
        if (blk < nblk) {
            const float* vp = v + (size_t)(s0 + blk * BS) * HIDDEN + tid;
            #pragma unroll
            for (int i = 0; i < BS; ++i) acc += vp[i * HIDDEN];
            acc *= (1.0f / BS);
        }
        v_cmp2[((size_t)(b * NH + h) * 32 + (blk >> 1)) * 128 + d * 2 + (blk & 1)] = acc;
    }
}

// Kernel 2 (unchanged): cmp scores + top-k + o_cmp. WG = (64-token tile, head).
__global__ __launch_bounds__(256, 3) void cmp_kernel(
    const float* __restrict__ q,
    const int* __restrict__ batch_ids, const int* __restrict__ pos_ids,
    const double* __restrict__ k_cmp, const float* __restrict__ v_cmp2,
    float* __restrict__ oc_buf, int2* __restrict__ idxbuf, int T) {
    int t0   = blockIdx.x * 64;        // tile within one sequence (lengths %256==0)
    int h    = blockIdx.y;
    int tid  = threadIdx.x;
    int wv   = __builtin_amdgcn_readfirstlane(tid >> 6);
    int lane = tid & 63;
    int b    = batch_ids[t0];          // uniform
    int pos0 = pos_ids[t0];            // positions contiguous in tile

    __shared__ __align__(16) char smem[49920];
    float* qs = (float*)smem;                       // [dd][65] padded, 16640 B
    float* ps = qs + 64 * 65;                       // [tok][66] padded, 16896 B
    float* vs = ps + 64 * 66;                       // 4096 floats, 16384 B
    unsigned long long* trip = (unsigned long long*)qs;  // reused after sync

    // stage q (transposed, padded) and v_cmp
    const float* qg = q + (size_t)t0 * HIDDEN + h * HD;
    #pragma unroll
    for (int i = 0; i < 16; ++i) {
        int idx = tid + 256 * i;                    // 4096 elements
        int tok = idx >> 6, dd = idx & 63;
        qs[dd * 65 + tok] = qg[(size_t)tok * HIDDEN + dd];
    }
    const float* vg = v_cmp2 + (size_t)(b * NH + h) * 4096;
    #pragma unroll
    for (int i = 0; i < 16; ++i) vs[tid + 256 * i] = vg[tid + 256 * i];
    __syncthreads();

    int qblk_max = (pos0 + 63) >> 5;
    int m_need   = qblk_max + 2;       // max block index any token's top-3 can touch
    if (m_need > 63) m_need = 63;

    unsigned long long a0 = 0ull, a1 = 0ull, a2 = 0ull;
    if (16 * wv <= m_need) {           // wave-uniform causal skip
        // per-lane (=token) q row in f64 registers
        double qd[64];
        #pragma unroll
        for (int dd = 0; dd < 64; ++dd) qd[dd] = (double)qs[dd * 65 + lane];
        int myqblk = (pos0 + lane) >> 5;

        const double* kcb = k_cmp + ((size_t)(b * NH + h) * 64 + wv * 16) * 64;
        #pragma unroll
        for (int mi = 0; mi < 16; ++mi) {
            int m = wv * 16 + mi;
            const double* kr = kcb + mi * 64;       // uniform -> s_load
            double accA = 0.0, accB = 0.0;          // 2-way split for ILP
            #pragma unroll
            for (int dd = 0; dd < 32; ++dd) {
                accA += qd[2 * dd]     * kr[2 * dd];
                accB += qd[2 * dd + 1] * kr[2 * dd + 1];
            }
            double r = (accA + accB) * 0.125;
            double p64 = 0.0;
            if (m <= myqblk) p64 = r / (1.0 + exp(-r)) * 8.0;   // silu*INV_SCALE
            double selv = (m == myqblk) ? 1.0 : p64;
            ps[lane * 66 + m] = (float)p64;         // exactly 0 beyond qblk
            long long sb = __double_as_longlong(selv);
            unsigned long long kk = (unsigned long long)sb;
            kk = (sb < 0) ? ~kk : (kk | 0x8000000000000000ull);
            kk = (kk & ~63ull) | (unsigned long long)(63 - m);
            // sorted insert (keys unique; predicated selects)
            if (kk > a0)      { a2 = a1; a1 = a0; a0 = kk; }
            else if (kk > a1) { a2 = a1; a1 = kk; }
            else if (kk > a2) { a2 = kk; }
        }
    }
    __syncthreads();                                // qs reads done -> reuse as trip
    trip[(wv * 64 + lane) * 3 + 0] = a0;
    trip[(wv * 64 + lane) * 3 + 1] = a1;
    trip[(wv * 64 + lane) * 3 + 2] = a2;
    __syncthreads();

    // merge 4 sorted triples (tournament, 3 picks); wave 0 stores idx
    if (wv == 0) {
        unsigned long long kk2[4][3];
        #pragma unroll
        for (int w = 0; w < 4; ++w)
            #pragma unroll
            for (int j = 0; j < 3; ++j)
                kk2[w][j] = trip[(w * 64 + lane) * 3 + j];
        int pp[4] = {0, 0, 0, 0};
        int outi[3];
        #pragma unroll
        for (int s = 0; s < 3; ++s) {
            unsigned long long best = 0ull; int bw = 0;
            #pragma unroll
            for (int w = 0; w < 4; ++w) {
                unsigned long long hd_ = (pp[w] == 0) ? kk2[w][0]
                                       : (pp[w] == 1) ? kk2[w][1] : kk2[w][2];
                if (hd_ > best) { best = hd_; bw = w; }
            }
            outi[s] = 63 - (int)(best & 63ull);
            #pragma unroll
            for (int w = 0; w < 4; ++w) if (w == bw) pp[w]++;
        }
        idxbuf[(size_t)(t0 + lane) * NH + h] = make_int2(outi[0], outi[2]);
    }

    // o_cmp: wave wv -> tokens [16wv,16wv+16), lane = d
    float occ[16];
    #pragma unroll
    for (int tt = 0; tt < 16; ++tt) occ[tt] = 0.f;
    int mmax2 = qblk_max >> 1;                      // pair bound, covers tile
    const float2* vs2 = (const float2*)vs;
    for (int m2 = 0; m2 <= mmax2; ++m2) {
        float2 vv = vs2[m2 * 64 + lane];
        #pragma unroll
        for (int tt = 0; tt < 16; ++tt) {
            int tok = wv * 16 + tt;
            float2 pv = *(const float2*)(ps + tok * 66 + 2 * m2);  // uniform b64
            occ[tt] += pv.x * vv.x + pv.y * vv.y;
        }
    }
    #pragma unroll
    for (int tt = 0; tt < 16; ++tt)
        oc_buf[(size_t)(t0 + wv * 16 + tt) * HIDDEN + h * HD + lane] = occ[tt];
}

// Kernel 3a (R16): slc gather, cross-token block sharing, 4 waves per WG.
// R15 post-mortem: launch_bounds(256,4) left VGPR_Count at 52 -> the allocator
// was NOT pressure-capped; instead the compiler SANK the vb[32] V loads into
// the token loop (occupancy heuristic), re-issuing 32 VMEM loads + a full
// L2/L3 round trip on EVERY token-iteration (~61/WG, serial). R16: pin the
// gathered K/V block in VGPRs with an empty inline-asm def+use per element
// (forbids sinking/remat), and split the serial FMA chains (ost 32-deep ->
// 2x16, psum 16-deep -> 2x8) for ILP. Diagnostic: VGPR must rise to ~100+.
__global__ __launch_bounds__(256, 4) void slc_kernel(
    const float* __restrict__ q, const float* __restrict__ k,
    const float* __restrict__ v,
    const int* __restrict__ x_offsets, const int* __restrict__ batch_ids,
    const int* __restrict__ pos_ids,
    const int2* __restrict__ idxbuf, float* __restrict__ os_out, int T) {
    int i  = blockIdx.x;
    int wg = (i & 7) * (gridDim.x >> 3) + (i >> 3);  // XCD chunks (grid %8==0)
    int qb = wg >> 2;             // q-block index (32 tokens)
    int h  = wg & 3;              // head
    int t0 = qb * 32;
    int tid  = threadIdx.x;
    int wv   = __builtin_amdgcn_readfirstlane(tid >> 6);
    int lane = tid & 63;

    int b    = batch_ids[t0];
    int pos0 = pos_ids[t0];       // q-blocks never straddle seqs (lengths %256==0)
    int s0   = x_offsets[b];
    int qblk = pos0 >> 5;         // uniform across the 32 tokens

    __shared__ float q_lds[32 * 68];   // [tk][68]: 64 dims + pad (16B-aligned rows)
    __shared__ float os_lds[32 * 64];  // [tk][d] o_slc accumulator (atomicAdd)

    // stage q head-slice: 512 float4 over 256 threads
    const float4* q4 = (const float4*)(q + (size_t)t0 * HIDDEN + h * HD);
    #pragma unroll
    for (int rep = 0; rep < 2; ++rep) {
        int f4i = tid + 256 * rep;
        int tk = f4i >> 4, c4 = f4i & 15;
        *(float4*)(&q_lds[tk * 68 + c4 * 4]) = q4[(size_t)tk * 64 + c4];
    }
    #pragma unroll
    for (int rep = 0; rep < 8; ++rep) os_lds[tid + 256 * rep] = 0.f;

    // per-token selections at lanes 0..31 (each wave loads its own copy);
    // invalid B-slot (idx2>qblk) dropped
    int myi0 = -1, myi2 = -1;
    unsigned long long U = 0ull;
    if (lane < 32) {
        int2 ix = idxbuf[(size_t)(t0 + lane) * NH + h];
        myi0 = ix.x;
        myi2 = (ix.y <= qblk) ? ix.y : -1;
        U = (1ull << myi0);
        if (myi2 >= 0) U |= (1ull << myi2);
    }
    #pragma unroll
    for (int off = 1; off < 64; off <<= 1) U |= __shfl_xor(U, off, 64);
    __syncthreads();

    int r  = lane & 15, cc = lane >> 4;
    const float* kbase = k + (size_t)s0 * HIDDEN + h * HD;
    const float* vbase = v + (size_t)s0 * HIDDEN + h * HD + lane;

    int cnt = 0;
    while (U) {
        int m = (int)__builtin_ctzll(U); U &= U - 1;
        if (((cnt++) & 3) != wv) continue;          // rank round-robin partition
        // gather K block m: lane (r,cc) holds rows {r, 16+r}, 16-float strip
        const float* kb_p = kbase + (size_t)(m * BS) * HIDDEN;
        float4 kb0[4], kb1[4];
        #pragma unroll
        for (int j = 0; j < 4; ++j) {
            kb0[j] = *(const float4*)(kb_p + (size_t)r * HIDDEN + (cc + 4 * j) * 4);
            kb1[j] = *(const float4*)(kb_p + (size_t)(16 + r) * HIDDEN + (cc + 4 * j) * 4);
        }
        // gather V block m: lane = d, 32 rows
        float vb[32];
        const float* vb_p = vbase + (size_t)(m * BS) * HIDDEN;
        #pragma unroll
        for (int row = 0; row < 32; ++row) vb[row] = vb_p[(size_t)row * HIDDEN];

        // PIN the gathered block in VGPRs: def+use barrier per element forbids
        // the compiler from sinking these loads into the token loop (the R15
        // failure mode: 32 VMEM loads + L2 round-trip per token-iteration).
        #pragma unroll
        for (int j = 0; j < 4; ++j) {
            asm volatile("" : "+v"(kb0[j].x), "+v"(kb0[j].y),
                              "+v"(kb0[j].z), "+v"(kb0[j].w));
            asm volatile("" : "+v"(kb1[j].x), "+v"(kb1[j].y),
                              "+v"(kb1[j].z), "+v"(kb1[j].w));
        }
        #pragma unroll
        for (int row = 0; row < 32; ++row) asm volatile("" : "+v"(vb[row]));

        unsigned long long want =
            __ballot(lane < 32 && (myi0 == m || myi2 == m));
        while (want) {
            int tk = (int)__builtin_ctzll(want); want &= want - 1;
            int pos_tk = pos0 + tk;
            const float* qrow = &q_lds[tk * 68];
            float psA0 = 0.f, psB0 = 0.f, psA1 = 0.f, psB1 = 0.f;  // 2-way ILP
            #pragma unroll
            for (int j = 0; j < 4; ++j) {
                float4 qq = *(const float4*)(qrow + (cc + 4 * j) * 4);
                if (j & 1) {
                    psB0 += qq.x * kb0[j].x + qq.y * kb0[j].y
                          + qq.z * kb0[j].z + qq.w * kb0[j].w;
                    psB1 += qq.x * kb1[j].x + qq.y * kb1[j].y
                          + qq.z * kb1[j].z + qq.w * kb1[j].w;
                } else {
                    psA0 += qq.x * kb0[j].x + qq.y * kb0[j].y
                          + qq.z * kb0[j].z + qq.w * kb0[j].w;
                    psA1 += qq.x * kb1[j].x + qq.y * kb1[j].y
                          + qq.z * kb1[j].z + qq.w * kb1[j].w;
                }
            }
            float psum0 = psA0 + psB0, psum1 = psA1 + psB1;
            psum0 += __shfl_xor(psum0, 16, 64); psum0 += __shfl_xor(psum0, 32, 64);
            psum1 += __shfl_xor(psum1, 16, 64); psum1 += __shfl_xor(psum1, 32, 64);
            float scv0 = psum0 * SCALE, scv1 = psum1 * SCALE;
            int row0 = m * BS + r;
            // weight 2: reference sums each distinct block twice (slot dup)
            float p0 = (row0 <= pos_tk)      ? scv0 * fast_sigmoid(scv0) * 16.f : 0.f;
            float p1 = (row0 + 16 <= pos_tk) ? scv1 * fast_sigmoid(scv1) * 16.f : 0.f;
            float ostA = 0.f, ostB = 0.f;           // split 32-deep chain -> 2x16
            #pragma unroll
            for (int rr = 0; rr < 16; ++rr) {
                ostA += readlane_f(p0, rr) * vb[rr];
                ostB += readlane_f(p1, rr) * vb[16 + rr];
            }
            atomicAdd(&os_lds[tk * 64 + lane], ostA + ostB);
        }
    }
    __syncthreads();

    // write o_slc (pre-LN) to os_out (= d_out, consumed+overwritten by ln_kernel)
    float* ob = os_out + (size_t)t0 * HIDDEN + h * HD;
    #pragma unroll
    for (int rep = 0; rep < 8; ++rep) {
        int idx = tid + 256 * rep;
        int tk = idx >> 6, d = idx & 63;
        ob[(size_t)tk * HIDDEN + d] = os_lds[idx];
    }
}

// Kernel 3b: gate + dual LayerNorm, streaming. WG = 8 tokens x 32 lanes
// (8 dims each). Reads oc_buf (raw o_cmp) and d_out (raw o_slc), writes final.
__global__ __launch_bounds__(256) void ln_kernel(
    const float* __restrict__ q, const float* __restrict__ u,
    const float* __restrict__ Wg_cmp,
    const float* __restrict__ oc_buf, float* __restrict__ io, int T) {
    int tid = threadIdx.x;
    int grp = tid >> 5;           // token within group of 8
    int sub = tid & 31;           // dim strip
    int t   = blockIdx.x * 8 + grp;
    int D0  = sub * 8;            // 8 dims per lane (all within one head)

    const float4* qp = (const float4*)(q + (size_t)t * HIDDEN + D0);
    float4 qa = qp[0], qb = qp[1];
    const float4* wp = (const float4*)(Wg_cmp + D0);   // [NH][64] flat = [256]
    float4 wa = wp[0], wb = wp[1];
    float gp = qa.x * wa.x + qa.y * wa.y + qa.z * wa.z + qa.w * wa.w
             + qb.x * wb.x + qb.y * wb.y + qb.z * wb.z + qb.w * wb.w;
    gp += __shfl_xor(gp, 1, 64);
    gp += __shfl_xor(gp, 2, 64);
    gp += __shfl_xor(gp, 4, 64);   // sum over the head's 8 lanes
    float g = fast_sigmoid(gp);

    const float4* ocp = (const float4*)(oc_buf + (size_t)t * HIDDEN + D0);
    float4 oa = ocp[0], ob = ocp[1];
    oa.x *= g; oa.y *= g; oa.z *= g; oa.w *= g;
    ob.x *= g; ob.y *= g; ob.z *= g; ob.w *= g;
    float4* iop = (float4*)(io + (size_t)t * HIDDEN + D0);
    float4 sa = iop[0], sb = iop[1];

    float sc_ = oa.x + oa.y + oa.z + oa.w + ob.x + ob.y + ob.z + ob.w;
    float sc2 = oa.x * oa.x + oa.y * oa.y + oa.z * oa.z + oa.w * oa.w
              + ob.x * ob.x + ob.y * ob.y + ob.z * ob.z + ob.w * ob.w;
    float ss_ = sa.x + sa.y + sa.z + sa.w + sb.x + sb.y + sb.z + sb.w;
    float ss2 = sa.x * sa.x + sa.y * sa.y + sa.z * sa.z + sa.w * sa.w
              + sb.x * sb.x + sb.y * sb.y + sb.z * sb.z + sb.w * sb.w;
    #pragma unroll
    for (int off = 1; off < 32; off <<= 1) {
        sc_ += __shfl_xor(sc_, off, 64);
        sc2 += __shfl_xor(sc2, off, 64);
        ss_ += __shfl_xor(ss_, off, 64);
        ss2 += __shfl_xor(ss2, off, 64);
    }
    float muc  = sc_ * (1.0f / HIDDEN);
    float varc = sc2 * (1.0f / HIDDEN) - muc * muc;
    float mus  = ss_ * (1.0f / HIDDEN);
    float vars = ss2 * (1.0f / HIDDEN) - mus * mus;
    float rc = rsqrtf(varc + 1e-6f), rs = rsqrtf(vars + 1e-6f);

    const float4* up = (const float4*)(u + (size_t)t * HIDDEN + D0);
    float4 ua = up[0], ub = up[1];
    float4 o0, o1;
    o0.x = ((oa.x - muc) * rc + (sa.x - mus) * rs) * ua.x;
    o0.y = ((oa.y - muc) * rc + (sa.y - mus) * rs) * ua.y;
    o0.z = ((oa.z - muc) * rc + (sa.z - mus) * rs) * ua.z;
    o0.w = ((oa.w - muc) * rc + (sa.w - mus) * rs) * ua.w;
    o1.x = ((ob.x - muc) * rc + (sb.x - mus) * rs) * ub.x;
    o1.y = ((ob.y - muc) * rc + (sb.y - mus) * rs) * ub.y;
    o1.z = ((ob.z - muc) * rc + (sb.z - mus) * rs) * ub.z;
    o1.w = ((ob.w - muc) * rc + (sb.w - mus) * rs) * ub.w;
    iop[0] = o0; iop[1] = o1;
}

extern "C" void kernel_launch(void* const* d_in, const int* in_sizes, int n_in,
                              void* d_out, int out_size, void* d_ws, size_t ws_size,
                              hipStream_t stream) {
    const float* q      = (const float*)d_in[0];
    const float* k      = (const float*)d_in[1];
    const float* v      = (const float*)d_in[2];
    const float* u      = (const float*)d_in[3];
    const float* Wg_cmp = (const float*)d_in[4];
    // d_in[5] = Wg_slc: dead code in the reference (computed, never used)
    const int* x_offsets = (const int*)d_in[6];
    const int* batch_ids = (const int*)d_in[7];
    const int* pos_ids   = (const int*)d_in[8];

    int T = in_sizes[0] / HIDDEN;   // 11008; all lengths are multiples of 256
    int B = in_sizes[6] - 1;

    double* k_cmp  = (double*)d_ws;                                 // B*NH*4096 doubles
    float*  v_cmp2 = (float*)(k_cmp + (size_t)B * NH * 4096);       // B*NH*4096 floats
    float*  oc_buf = v_cmp2 + (size_t)B * NH * 4096;                // T*256 floats
    int2*   idxbuf = (int2*)(oc_buf + (size_t)T * HIDDEN);          // T*NH int2

    kcmp_kernel<<<dim3(B * NB, 2), 256, 0, stream>>>(k, v, x_offsets, k_cmp, v_cmp2);
    cmp_kernel<<<dim3(T / 64, NH), 256, 0, stream>>>(
        q, batch_ids, pos_ids, k_cmp, v_cmp2, oc_buf, idxbuf, T);
    // 3a: o_slc (pre-LN) staged into d_out; 3b: gate + LN overwrite d_out
    slc_kernel<<<dim3((T / 32) * NH), 256, 0, stream>>>(
        q, k, v, x_offsets, batch_ids, pos_ids, idxbuf, (float*)d_out, T);
    ln_kernel<<<dim3(T / 8), 256, 0, stream>>>(
        q, u, Wg_cmp, oc_buf, (float*)d_out, T);
}

// Round 7
// 210.783 us; speedup vs baseline: 1.0098x; 1.0098x over previous
//
#include <hip/hip_runtime.h>
#include <math.h>

// Problem constants (from reference)
#define NH 4
#define HD 64
#define HIDDEN 256
#define BS 32
#define NB 64          // NUM_BLOCKS = MAX_LEN/BS = 2048/32
#define SCALE 0.125f
#define INV_SCALE 8.0f

__device__ __forceinline__ float fast_sigmoid(float x) {
    return 1.0f / (1.0f + __expf(-x));
}
__device__ __forceinline__ float readlane_f(float v, int lane) {
    return __int_as_float(__builtin_amdgcn_readlane(__float_as_int(v), lane));
}

// Kernel 1 (unchanged): block means. K in f64 (selection path f64-exact vs np
// reference), V in f32.
__global__ __launch_bounds__(256) void kcmp_kernel(
    const float* __restrict__ k, const float* __restrict__ v,
    const int* __restrict__ x_offsets,
    double* __restrict__ k_cmp, float* __restrict__ v_cmp2) {
    int bb  = blockIdx.x;          // b*NB + blk
    int b   = bb >> 6;
    int blk = bb & 63;
    int tid = threadIdx.x;         // column: h = tid>>6, d = tid&63
    int s0   = x_offsets[b];
    int len  = x_offsets[b + 1] - s0;
    int nblk = len >> 5;
    int h = tid >> 6, d = tid & 63;
    if (blockIdx.y == 0) {
        double acc = 0.0;
        if (blk < nblk) {
            const float* kp = k + (size_t)(s0 + blk * BS) * HIDDEN + tid;
            #pragma unroll
            for (int i = 0; i < BS; ++i) acc += (double)kp[i * HIDDEN];
            acc *= (1.0 / BS);
        }
        k_cmp[((size_t)(b * NH + h) * 64 + blk) * 64 + d] = acc;
    } else {
        float acc = 0.f;
        if (blk < nblk) {
            const float* vp = v + (size_t)(s0 + blk * BS) * HIDDEN + tid;
            #pragma unroll
            for (int i = 0; i < BS; ++i) acc += vp[i * HIDDEN];
            acc *= (1.0f / BS);
        }
        v_cmp2[((size_t)(b * NH + h) * 32 + (blk >> 1)) * 128 + d * 2 + (blk & 1)] = acc;
    }
}

// Kernel 2 (unchanged): cmp scores + top-k + o_cmp. WG = (64-token tile, head).
__global__ __launch_bounds__(256, 3) void cmp_kernel(
    const float* __restrict__ q,
    const int* __restrict__ batch_ids, const int* __restrict__ pos_ids,
    const double* __restrict__ k_cmp, const float* __restrict__ v_cmp2,
    float* __restrict__ oc_buf, int2* __restrict__ idxbuf, int T) {
    int t0   = blockIdx.x * 64;        // tile within one sequence (lengths %256==0)
    int h    = blockIdx.y;
    int tid  = threadIdx.x;
    int wv   = __builtin_amdgcn_readfirstlane(tid >> 6);
    int lane = tid & 63;
    int b    = batch_ids[t0];          // uniform
    int pos0 = pos_ids[t0];            // positions contiguous in tile

    __shared__ __align__(16) char smem[49920];
    float* qs = (float*)smem;                       // [dd][65] padded, 16640 B
    float* ps = qs + 64 * 65;                       // [tok][66] padded, 16896 B
    float* vs = ps + 64 * 66;                       // 4096 floats, 16384 B
    unsigned long long* trip = (unsigned long long*)qs;  // reused after sync

    // stage q (transposed, padded) and v_cmp
    const float* qg = q + (size_t)t0 * HIDDEN + h * HD;
    #pragma unroll
    for (int i = 0; i < 16; ++i) {
        int idx = tid + 256 * i;                    // 4096 elements
        int tok = idx >> 6, dd = idx & 63;
        qs[dd * 65 + tok] = qg[(size_t)tok * HIDDEN + dd];
    }
    const float* vg = v_cmp2 + (size_t)(b * NH + h) * 4096;
    #pragma unroll
    for (int i = 0; i < 16; ++i) vs[tid + 256 * i] = vg[tid + 256 * i];
    __syncthreads();

    int qblk_max = (pos0 + 63) >> 5;
    int m_need   = qblk_max + 2;       // max block index any token's top-3 can touch
    if (m_need > 63) m_need = 63;

    unsigned long long a0 = 0ull, a1 = 0ull, a2 = 0ull;
    if (16 * wv <= m_need) {           // wave-uniform causal skip
        // per-lane (=token) q row in f64 registers
        double qd[64];
        #pragma unroll
        for (int dd = 0; dd < 64; ++dd) qd[dd] = (double)qs[dd * 65 + lane];
        int myqblk = (pos0 + lane) >> 5;

        const double* kcb = k_cmp + ((size_t)(b * NH + h) * 64 + wv * 16) * 64;
        #pragma unroll
        for (int mi = 0; mi < 16; ++mi) {
            int m = wv * 16 + mi;
            const double* kr = kcb + mi * 64;       // uniform -> s_load
            double accA = 0.0, accB = 0.0;          // 2-way split for ILP
            #pragma unroll
            for (int dd = 0; dd < 32; ++dd) {
                accA += qd[2 * dd]     * kr[2 * dd];
                accB += qd[2 * dd + 1] * kr[2 * dd + 1];
            }
            double r = (accA + accB) * 0.125;
            double p64 = 0.0;
            if (m <= myqblk) p64 = r / (1.0 + exp(-r)) * 8.0;   // silu*INV_SCALE
            double selv = (m == myqblk) ? 1.0 : p64;
            ps[lane * 66 + m] = (float)p64;         // exactly 0 beyond qblk
            long long sb = __double_as_longlong(selv);
            unsigned long long kk = (unsigned long long)sb;
            kk = (sb < 0) ? ~kk : (kk | 0x8000000000000000ull);
            kk = (kk & ~63ull) | (unsigned long long)(63 - m);
            // sorted insert (keys unique; predicated selects)
            if (kk > a0)      { a2 = a1; a1 = a0; a0 = kk; }
            else if (kk > a1) { a2 = a1; a1 = kk; }
            else if (kk > a2) { a2 = kk; }
        }
    }
    __syncthreads();                                // qs reads done -> reuse as trip
    trip[(wv * 64 + lane) * 3 + 0] = a0;
    trip[(wv * 64 + lane) * 3 + 1] = a1;
    trip[(wv * 64 + lane) * 3 + 2] = a2;
    __syncthreads();

    // merge 4 sorted triples (tournament, 3 picks); wave 0 stores idx
    if (wv == 0) {
        unsigned long long kk2[4][3];
        #pragma unroll
        for (int w = 0; w < 4; ++w)
            #pragma unroll
            for (int j = 0; j < 3; ++j)
                kk2[w][j] = trip[(w * 64 + lane) * 3 + j];
        int pp[4] = {0, 0, 0, 0};
        int outi[3];
        #pragma unroll
        for (int s = 0; s < 3; ++s) {
            unsigned long long best = 0ull; int bw = 0;
            #pragma unroll
            for (int w = 0; w < 4; ++w) {
                unsigned long long hd_ = (pp[w] == 0) ? kk2[w][0]
                                       : (pp[w] == 1) ? kk2[w][1] : kk2[w][2];
                if (hd_ > best) { best = hd_; bw = w; }
            }
            outi[s] = 63 - (int)(best & 63ull);
            #pragma unroll
            for (int w = 0; w < 4; ++w) if (w == bw) pp[w]++;
        }
        idxbuf[(size_t)(t0 + lane) * NH + h] = make_int2(outi[0], outi[2]);
    }

    // o_cmp: wave wv -> tokens [16wv,16wv+16), lane = d
    float occ[16];
    #pragma unroll
    for (int tt = 0; tt < 16; ++tt) occ[tt] = 0.f;
    int mmax2 = qblk_max >> 1;                      // pair bound, covers tile
    const float2* vs2 = (const float2*)vs;
    for (int m2 = 0; m2 <= mmax2; ++m2) {
        float2 vv = vs2[m2 * 64 + lane];
        #pragma unroll
        for (int tt = 0; tt < 16; ++tt) {
            int tok = wv * 16 + tt;
            float2 pv = *(const float2*)(ps + tok * 66 + 2 * m2);  // uniform b64
            occ[tt] += pv.x * vv.x + pv.y * vv.y;
        }
    }
    #pragma unroll
    for (int tt = 0; tt < 16; ++tt)
        oc_buf[(size_t)(t0 + wv * 16 + tt) * HIDDEN + h * HD + lane] = occ[tt];
}

// Kernel 3a (R17): slc gather, cross-token block sharing, 4 waves per WG.
// R16 post-mortem: VGPR_Count stuck at 52 => vb[32] was allocated in SCRATCH
// (private mem) all along; the token loop paid ~32 scratch loads per
// iteration (~1.5-2K cy) -> 32us wave lifetimes, invariant to wave count,
// VALUBusy pinned ~27%. Scratch is L2-absorbed so FETCH/WRITE never showed it.
// R17: V goes to LDS (per-wave [32][64] buffer, 4x8KB). Staging uses groups
// of 8 NAMED scalars (registers, rule #20). PV reads vs_w[row*64+lane]:
// stride-1 across lanes -> 2-way bank aliasing (free), 32 independent
// ds_reads pipeline. K stays in VGPRs (fits: 52 = 32 kb + 20 misc) with pins.
__global__ __launch_bounds__(256) void slc_kernel(
    const float* __restrict__ q, const float* __restrict__ k,
    const float* __restrict__ v,
    const int* __restrict__ x_offsets, const int* __restrict__ batch_ids,
    const int* __restrict__ pos_ids,
    const int2* __restrict__ idxbuf, float* __restrict__ os_out, int T) {
    int i  = blockIdx.x;
    int wg = (i & 7) * (gridDim.x >> 3) + (i >> 3);  // XCD chunks (grid %8==0)
    int qb = wg >> 2;             // q-block index (32 tokens)
    int h  = wg & 3;              // head
    int t0 = qb * 32;
    int tid  = threadIdx.x;
    int wv   = __builtin_amdgcn_readfirstlane(tid >> 6);
    int lane = tid & 63;

    int b    = batch_ids[t0];
    int pos0 = pos_ids[t0];       // q-blocks never straddle seqs (lengths %256==0)
    int s0   = x_offsets[b];
    int qblk = pos0 >> 5;         // uniform across the 32 tokens

    __shared__ float q_lds[32 * 68];     // [tk][68] padded q rows, 8704 B
    __shared__ float os_lds[32 * 64];    // [tk][d] o_slc accumulator, 8192 B
    __shared__ float vs_lds[4 * 32 * 64];// per-wave V block [32 rows][64 d], 32768 B
    float* vs_w = vs_lds + wv * 2048;

    // stage q head-slice: 512 float4 over 256 threads
    const float4* q4 = (const float4*)(q + (size_t)t0 * HIDDEN + h * HD);
    #pragma unroll
    for (int rep = 0; rep < 2; ++rep) {
        int f4i = tid + 256 * rep;
        int tk = f4i >> 4, c4 = f4i & 15;
        *(float4*)(&q_lds[tk * 68 + c4 * 4]) = q4[(size_t)tk * 64 + c4];
    }
    #pragma unroll
    for (int rep = 0; rep < 8; ++rep) os_lds[tid + 256 * rep] = 0.f;

    // per-token selections at lanes 0..31 (each wave loads its own copy);
    // invalid B-slot (idx2>qblk) dropped
    int myi0 = -1, myi2 = -1;
    unsigned long long U = 0ull;
    if (lane < 32) {
        int2 ix = idxbuf[(size_t)(t0 + lane) * NH + h];
        myi0 = ix.x;
        myi2 = (ix.y <= qblk) ? ix.y : -1;
        U = (1ull << myi0);
        if (myi2 >= 0) U |= (1ull << myi2);
    }
    #pragma unroll
    for (int off = 1; off < 64; off <<= 1) U |= __shfl_xor(U, off, 64);
    __syncthreads();

    int r  = lane & 15, cc = lane >> 4;
    const float* kbase = k + (size_t)s0 * HIDDEN + h * HD;
    const float* vbase = v + (size_t)s0 * HIDDEN + h * HD + lane;

    int cnt = 0;
    while (U) {
        int m = (int)__builtin_ctzll(U); U &= U - 1;
        if (((cnt++) & 3) != wv) continue;          // rank round-robin partition
        // gather K block m: lane (r,cc) holds rows {r, 16+r}, 16-float strip
        const float* kb_p = kbase + (size_t)(m * BS) * HIDDEN;
        float4 kb0[4], kb1[4];
        #pragma unroll
        for (int j = 0; j < 4; ++j) {
            kb0[j] = *(const float4*)(kb_p + (size_t)r * HIDDEN + (cc + 4 * j) * 4);
            kb1[j] = *(const float4*)(kb_p + (size_t)(16 + r) * HIDDEN + (cc + 4 * j) * 4);
        }
        // stage V block m into this wave's LDS buffer: groups of 8 named
        // scalars (registers) -> 8 loads in flight, then 8 ds_writes.
        {
            const float* vb_p = vbase + (size_t)(m * BS) * HIDDEN;
            #pragma unroll
            for (int g = 0; g < 4; ++g) {
                const float* p0_ = vb_p + (size_t)(g * 8) * HIDDEN;
                float x0 = p0_[0 * HIDDEN], x1 = p0_[1 * HIDDEN];
                float x2 = p0_[2 * HIDDEN], x3 = p0_[3 * HIDDEN];
                float x4 = p0_[4 * HIDDEN], x5 = p0_[5 * HIDDEN];
                float x6 = p0_[6 * HIDDEN], x7 = p0_[7 * HIDDEN];
                float* d0 = vs_w + (g * 8) * 64 + lane;
                d0[0 * 64] = x0; d0[1 * 64] = x1; d0[2 * 64] = x2; d0[3 * 64] = x3;
                d0[4 * 64] = x4; d0[5 * 64] = x5; d0[6 * 64] = x6; d0[7 * 64] = x7;
            }
        }
        // pin K block in VGPRs (R15 failure mode: loads sunk into token loop)
        #pragma unroll
        for (int j = 0; j < 4; ++j) {
            asm volatile("" : "+v"(kb0[j].x), "+v"(kb0[j].y),
                              "+v"(kb0[j].z), "+v"(kb0[j].w));
            asm volatile("" : "+v"(kb1[j].x), "+v"(kb1[j].y),
                              "+v"(kb1[j].z), "+v"(kb1[j].w));
        }

        unsigned long long want =
            __ballot(lane < 32 && (myi0 == m || myi2 == m));
        while (want) {
            int tk = (int)__builtin_ctzll(want); want &= want - 1;
            int pos_tk = pos0 + tk;
            const float* qrow = &q_lds[tk * 68];
            float psA0 = 0.f, psB0 = 0.f, psA1 = 0.f, psB1 = 0.f;  // 2-way ILP
            #pragma unroll
            for (int j = 0; j < 4; ++j) {
                float4 qq = *(const float4*)(qrow + (cc + 4 * j) * 4);
                if (j & 1) {
                    psB0 += qq.x * kb0[j].x + qq.y * kb0[j].y
                          + qq.z * kb0[j].z + qq.w * kb0[j].w;
                    psB1 += qq.x * kb1[j].x + qq.y * kb1[j].y
                          + qq.z * kb1[j].z + qq.w * kb1[j].w;
                } else {
                    psA0 += qq.x * kb0[j].x + qq.y * kb0[j].y
                          + qq.z * kb0[j].z + qq.w * kb0[j].w;
                    psA1 += qq.x * kb1[j].x + qq.y * kb1[j].y
                          + qq.z * kb1[j].z + qq.w * kb1[j].w;
                }
            }
            float psum0 = psA0 + psB0, psum1 = psA1 + psB1;
            psum0 += __shfl_xor(psum0, 16, 64); psum0 += __shfl_xor(psum0, 32, 64);
            psum1 += __shfl_xor(psum1, 16, 64); psum1 += __shfl_xor(psum1, 32, 64);
            float scv0 = psum0 * SCALE, scv1 = psum1 * SCALE;
            int row0 = m * BS + r;
            // weight 2: reference sums each distinct block twice (slot dup)
            float p0 = (row0 <= pos_tk)      ? scv0 * fast_sigmoid(scv0) * 16.f : 0.f;
            float p1 = (row0 + 16 <= pos_tk) ? scv1 * fast_sigmoid(scv1) * 16.f : 0.f;
            // PV: V from LDS (stride-1 across lanes, free 2-way aliasing),
            // P broadcast via readlane; two independent 16-deep chains.
            float ostA = 0.f, ostB = 0.f;
            #pragma unroll
            for (int rr = 0; rr < 16; ++rr) {
                ostA += readlane_f(p0, rr) * vs_w[rr * 64 + lane];
                ostB += readlane_f(p1, rr) * vs_w[(16 + rr) * 64 + lane];
            }
            atomicAdd(&os_lds[tk * 64 + lane], ostA + ostB);
        }
    }
    __syncthreads();

    // write o_slc (pre-LN) to os_out (= d_out, consumed+overwritten by ln_kernel)
    float* ob = os_out + (size_t)t0 * HIDDEN + h * HD;
    #pragma unroll
    for (int rep = 0; rep < 8; ++rep) {
        int idx = tid + 256 * rep;
        int tk = idx >> 6, d = idx & 63;
        ob[(size_t)tk * HIDDEN + d] = os_lds[idx];
    }
}

// Kernel 3b: gate + dual LayerNorm, streaming. WG = 8 tokens x 32 lanes
// (8 dims each). Reads oc_buf (raw o_cmp) and d_out (raw o_slc), writes final.
__global__ __launch_bounds__(256) void ln_kernel(
    const float* __restrict__ q, const float* __restrict__ u,
    const float* __restrict__ Wg_cmp,
    const float* __restrict__ oc_buf, float* __restrict__ io, int T) {
    int tid = threadIdx.x;
    int grp = tid >> 5;           // token within group of 8
    int sub = tid & 31;           // dim strip
    int t   = blockIdx.x * 8 + grp;
    int D0  = sub * 8;            // 8 dims per lane (all within one head)

    const float4* qp = (const float4*)(q + (size_t)t * HIDDEN + D0);
    float4 qa = qp[0], qb = qp[1];
    const float4* wp = (const float4*)(Wg_cmp + D0);   // [NH][64] flat = [256]
    float4 wa = wp[0], wb = wp[1];
    float gp = qa.x * wa.x + qa.y * wa.y + qa.z * wa.z + qa.w * wa.w
             + qb.x * wb.x + qb.y * wb.y + qb.z * wb.z + qb.w * wb.w;
    gp += __shfl_xor(gp, 1, 64);
    gp += __shfl_xor(gp, 2, 64);
    gp += __shfl_xor(gp, 4, 64);   // sum over the head's 8 lanes
    float g = fast_sigmoid(gp);

    const float4* ocp = (const float4*)(oc_buf + (size_t)t * HIDDEN + D0);
    float4 oa = ocp[0], ob = ocp[1];
    oa.x *= g; oa.y *= g; oa.z *= g; oa.w *= g;
    ob.x *= g; ob.y *= g; ob.z *= g; ob.w *= g;
    float4* iop = (float4*)(io + (size_t)t * HIDDEN + D0);
    float4 sa = iop[0], sb = iop[1];

    float sc_ = oa.x + oa.y + oa.z + oa.w + ob.x + ob.y + ob.z + ob.w;
    float sc2 = oa.x * oa.x + oa.y * oa.y + oa.z * oa.z + oa.w * oa.w
              + ob.x * ob.x + ob.y * ob.y + ob.z * ob.z + ob.w * ob.w;
    float ss_ = sa.x + sa.y + sa.z + sa.w + sb.x + sb.y + sb.z + sb.w;
    float ss2 = sa.x * sa.x + sa.y * sa.y + sa.z * sa.z + sa.w * sa.w
              + sb.x * sb.x + sb.y * sb.y + sb.z * sb.z + sb.w * sb.w;
    #pragma unroll
    for (int off = 1; off < 32; off <<= 1) {
        sc_ += __shfl_xor(sc_, off, 64);
        sc2 += __shfl_xor(sc2, off, 64);
        ss_ += __shfl_xor(ss_, off, 64);
        ss2 += __shfl_xor(ss2, off, 64);
    }
    float muc  = sc_ * (1.0f / HIDDEN);
    float varc = sc2 * (1.0f / HIDDEN) - muc * muc;
    float mus  = ss_ * (1.0f / HIDDEN);
    float vars = ss2 * (1.0f / HIDDEN) - mus * mus;
    float rc = rsqrtf(varc + 1e-6f), rs = rsqrtf(vars + 1e-6f);

    const float4* up = (const float4*)(u + (size_t)t * HIDDEN + D0);
    float4 ua = up[0], ub = up[1];
    float4 o0, o1;
    o0.x = ((oa.x - muc) * rc + (sa.x - mus) * rs) * ua.x;
    o0.y = ((oa.y - muc) * rc + (sa.y - mus) * rs) * ua.y;
    o0.z = ((oa.z - muc) * rc + (sa.z - mus) * rs) * ua.z;
    o0.w = ((oa.w - muc) * rc + (sa.w - mus) * rs) * ua.w;
    o1.x = ((ob.x - muc) * rc + (sb.x - mus) * rs) * ub.x;
    o1.y = ((ob.y - muc) * rc + (sb.y - mus) * rs) * ub.y;
    o1.z = ((ob.z - muc) * rc + (sb.z - mus) * rs) * ub.z;
    o1.w = ((ob.w - muc) * rc + (sb.w - mus) * rs) * ub.w;
    iop[0] = o0; iop[1] = o1;
}

extern "C" void kernel_launch(void* const* d_in, const int* in_sizes, int n_in,
                              void* d_out, int out_size, void* d_ws, size_t ws_size,
                              hipStream_t stream) {
    const float* q      = (const float*)d_in[0];
    const float* k      = (const float*)d_in[1];
    const float* v      = (const float*)d_in[2];
    const float* u      = (const float*)d_in[3];
    const float* Wg_cmp = (const float*)d_in[4];
    // d_in[5] = Wg_slc: dead code in the reference (computed, never used)
    const int* x_offsets = (const int*)d_in[6];
    const int* batch_ids = (const int*)d_in[7];
    const int* pos_ids   = (const int*)d_in[8];

    int T = in_sizes[0] / HIDDEN;   // 11008; all lengths are multiples of 256
    int B = in_sizes[6] - 1;

    double* k_cmp  = (double*)d_ws;                                 // B*NH*4096 doubles
    float*  v_cmp2 = (float*)(k_cmp + (size_t)B * NH * 4096);       // B*NH*4096 floats
    float*  oc_buf = v_cmp2 + (size_t)B * NH * 4096;                // T*256 floats
    int2*   idxbuf = (int2*)(oc_buf + (size_t)T * HIDDEN);          // T*NH int2

    kcmp_kernel<<<dim3(B * NB, 2), 256, 0, stream>>>(k, v, x_offsets, k_cmp, v_cmp2);
    cmp_kernel<<<dim3(T / 64, NH), 256, 0, stream>>>(
        q, batch_ids, pos_ids, k_cmp, v_cmp2, oc_buf, idxbuf, T);
    // 3a: o_slc (pre-LN) staged into d_out; 3b: gate + LN overwrite d_out
    slc_kernel<<<dim3((T / 32) * NH), 256, 0, stream>>>(
        q, k, v, x_offsets, batch_ids, pos_ids, idxbuf, (float*)d_out, T);
    ln_kernel<<<dim3(T / 8), 256, 0, stream>>>(
        q, u, Wg_cmp, oc_buf, (float*)d_out, T);
}

// Round 8
// 206.041 us; speedup vs baseline: 1.0331x; 1.0230x over previous
//
#include <hip/hip_runtime.h>
#include <math.h>

// Problem constants (from reference)
#define NH 4
#define HD 64
#define HIDDEN 256
#define BS 32
#define NB 64          // NUM_BLOCKS = MAX_LEN/BS = 2048/32
#define SCALE 0.125f
#define INV_SCALE 8.0f

__device__ __forceinline__ float fast_sigmoid(float x) {
    return 1.0f / (1.0f + __expf(-x));
}
__device__ __forceinline__ float readlane_f(float v, int lane) {
    return __int_as_float(__builtin_amdgcn_readlane(__float_as_int(v), lane));
}

// Kernel 1 (unchanged): block means. K in f64 (selection path f64-exact vs np
// reference), V in f32.
__global__ __launch_bounds__(256) void kcmp_kernel(
    const float* __restrict__ k, const float* __restrict__ v,
    const int* __restrict__ x_offsets,
    double* __restrict__ k_cmp, float* __restrict__ v_cmp2) {
    int bb  = blockIdx.x;          // b*NB + blk
    int b   = bb >> 6;
    int blk = bb & 63;
    int tid = threadIdx.x;         // column: h = tid>>6, d = tid&63
    int s0   = x_offsets[b];
    int len  = x_offsets[b + 1] - s0;
    int nblk = len >> 5;
    int h = tid >> 6, d = tid & 63;
    if (blockIdx.y == 0) {
        double acc = 0.0;
        if (blk < nblk) {
            const float* kp = k + (size_t)(s0 + blk * BS) * HIDDEN + tid;
            #pragma unroll
            for (int i = 0; i < BS; ++i) acc += (double)kp[i * HIDDEN];
            acc *= (1.0 / BS);
        }
        k_cmp[((size_t)(b * NH + h) * 64 + blk) * 64 + d] = acc;
    } else {
        float acc = 0.f;
        if (blk < nblk) {
            const float* vp = v + (size_t)(s0 + blk * BS) * HIDDEN + tid;
            #pragma unroll
            for (int i = 0; i < BS; ++i) acc += vp[i * HIDDEN];
            acc *= (1.0f / BS);
        }
        v_cmp2[((size_t)(b * NH + h) * 32 + (blk >> 1)) * 128 + d * 2 + (blk & 1)] = acc;
    }
}

// Kernel 2 (unchanged): cmp scores + top-k + o_cmp. WG = (64-token tile, head).
__global__ __launch_bounds__(256, 3) void cmp_kernel(
    const float* __restrict__ q,
    const int* __restrict__ batch_ids, const int* __restrict__ pos_ids,
    const double* __restrict__ k_cmp, const float* __restrict__ v_cmp2,
    float* __restrict__ oc_buf, int2* __restrict__ idxbuf, int T) {
    int t0   = blockIdx.x * 64;        // tile within one sequence (lengths %256==0)
    int h    = blockIdx.y;
    int tid  = threadIdx.x;
    int wv   = __builtin_amdgcn_readfirstlane(tid >> 6);
    int lane = tid & 63;
    int b    = batch_ids[t0];          // uniform
    int pos0 = pos_ids[t0];            // positions contiguous in tile

    __shared__ __align__(16) char smem[49920];
    float* qs = (float*)smem;                       // [dd][65] padded, 16640 B
    float* ps = qs + 64 * 65;                       // [tok][66] padded, 16896 B
    float* vs = ps + 64 * 66;                       // 4096 floats, 16384 B
    unsigned long long* trip = (unsigned long long*)qs;  // reused after sync

    // stage q (transposed, padded) and v_cmp
    const float* qg = q + (size_t)t0 * HIDDEN + h * HD;
    #pragma unroll
    for (int i = 0; i < 16; ++i) {
        int idx = tid + 256 * i;                    // 4096 elements
        int tok = idx >> 6, dd = idx & 63;
        qs[dd * 65 + tok] = qg[(size_t)tok * HIDDEN + dd];
    }
    const float* vg = v_cmp2 + (size_t)(b * NH + h) * 4096;
    #pragma unroll
    for (int i = 0; i < 16; ++i) vs[tid + 256 * i] = vg[tid + 256 * i];
    __syncthreads();

    int qblk_max = (pos0 + 63) >> 5;
    int m_need   = qblk_max + 2;       // max block index any token's top-3 can touch
    if (m_need > 63) m_need = 63;

    unsigned long long a0 = 0ull, a1 = 0ull, a2 = 0ull;
    if (16 * wv <= m_need) {           // wave-uniform causal skip
        // per-lane (=token) q row in f64 registers
        double qd[64];
        #pragma unroll
        for (int dd = 0; dd < 64; ++dd) qd[dd] = (double)qs[dd * 65 + lane];
        int myqblk = (pos0 + lane) >> 5;

        const double* kcb = k_cmp + ((size_t)(b * NH + h) * 64 + wv * 16) * 64;
        #pragma unroll
        for (int mi = 0; mi < 16; ++mi) {
            int m = wv * 16 + mi;
            const double* kr = kcb + mi * 64;       // uniform -> s_load
            double accA = 0.0, accB = 0.0;          // 2-way split for ILP
            #pragma unroll
            for (int dd = 0; dd < 32; ++dd) {
                accA += qd[2 * dd]     * kr[2 * dd];
                accB += qd[2 * dd + 1] * kr[2 * dd + 1];
            }
            double r = (accA + accB) * 0.125;
            double p64 = 0.0;
            if (m <= myqblk) p64 = r / (1.0 + exp(-r)) * 8.0;   // silu*INV_SCALE
            double selv = (m == myqblk) ? 1.0 : p64;
            ps[lane * 66 + m] = (float)p64;         // exactly 0 beyond qblk
            long long sb = __double_as_longlong(selv);
            unsigned long long kk = (unsigned long long)sb;
            kk = (sb < 0) ? ~kk : (kk | 0x8000000000000000ull);
            kk = (kk & ~63ull) | (unsigned long long)(63 - m);
            // sorted insert (keys unique; predicated selects)
            if (kk > a0)      { a2 = a1; a1 = a0; a0 = kk; }
            else if (kk > a1) { a2 = a1; a1 = kk; }
            else if (kk > a2) { a2 = kk; }
        }
    }
    __syncthreads();                                // qs reads done -> reuse as trip
    trip[(wv * 64 + lane) * 3 + 0] = a0;
    trip[(wv * 64 + lane) * 3 + 1] = a1;
    trip[(wv * 64 + lane) * 3 + 2] = a2;
    __syncthreads();

    // merge 4 sorted triples (tournament, 3 picks); wave 0 stores idx
    if (wv == 0) {
        unsigned long long kk2[4][3];
        #pragma unroll
        for (int w = 0; w < 4; ++w)
            #pragma unroll
            for (int j = 0; j < 3; ++j)
                kk2[w][j] = trip[(w * 64 + lane) * 3 + j];
        int pp[4] = {0, 0, 0, 0};
        int outi[3];
        #pragma unroll
        for (int s = 0; s < 3; ++s) {
            unsigned long long best = 0ull; int bw = 0;
            #pragma unroll
            for (int w = 0; w < 4; ++w) {
                unsigned long long hd_ = (pp[w] == 0) ? kk2[w][0]
                                       : (pp[w] == 1) ? kk2[w][1] : kk2[w][2];
                if (hd_ > best) { best = hd_; bw = w; }
            }
            outi[s] = 63 - (int)(best & 63ull);
            #pragma unroll
            for (int w = 0; w < 4; ++w) if (w == bw) pp[w]++;
        }
        idxbuf[(size_t)(t0 + lane) * NH + h] = make_int2(outi[0], outi[2]);
    }

    // o_cmp: wave wv -> tokens [16wv,16wv+16), lane = d
    float occ[16];
    #pragma unroll
    for (int tt = 0; tt < 16; ++tt) occ[tt] = 0.f;
    int mmax2 = qblk_max >> 1;                      // pair bound, covers tile
    const float2* vs2 = (const float2*)vs;
    for (int m2 = 0; m2 <= mmax2; ++m2) {
        float2 vv = vs2[m2 * 64 + lane];
        #pragma unroll
        for (int tt = 0; tt < 16; ++tt) {
            int tok = wv * 16 + tt;
            float2 pv = *(const float2*)(ps + tok * 66 + 2 * m2);  // uniform b64
            occ[tt] += pv.x * vv.x + pv.y * vv.y;
        }
    }
    #pragma unroll
    for (int tt = 0; tt < 16; ++tt)
        oc_buf[(size_t)(t0 + wv * 16 + tt) * HIDDEN + h * HD + lane] = occ[tt];
}

// Score of token tk against the resident K block (rows r, 16+r per lane):
// FP-order identical to R17's per-token computation.
#define SCORE_TOK(tk, P0, P1) do {                                            \
    int pos_tk = pos0 + (tk);                                                 \
    const float* qrow = &q_lds[(tk) * 68];                                    \
    float psA0 = 0.f, psB0 = 0.f, psA1 = 0.f, psB1 = 0.f;                     \
    _Pragma("unroll")                                                         \
    for (int j = 0; j < 4; ++j) {                                             \
        float4 qq = *(const float4*)(qrow + (cc + 4 * j) * 4);                \
        if (j & 1) {                                                          \
            psB0 += qq.x * kb0[j].x + qq.y * kb0[j].y                         \
                  + qq.z * kb0[j].z + qq.w * kb0[j].w;                        \
            psB1 += qq.x * kb1[j].x + qq.y * kb1[j].y                         \
                  + qq.z * kb1[j].z + qq.w * kb1[j].w;                        \
        } else {                                                              \
            psA0 += qq.x * kb0[j].x + qq.y * kb0[j].y                         \
                  + qq.z * kb0[j].z + qq.w * kb0[j].w;                        \
            psA1 += qq.x * kb1[j].x + qq.y * kb1[j].y                         \
                  + qq.z * kb1[j].z + qq.w * kb1[j].w;                        \
        }                                                                     \
    }                                                                         \
    float psum0 = psA0 + psB0, psum1 = psA1 + psB1;                           \
    psum0 += __shfl_xor(psum0, 16, 64); psum0 += __shfl_xor(psum0, 32, 64);   \
    psum1 += __shfl_xor(psum1, 16, 64); psum1 += __shfl_xor(psum1, 32, 64);   \
    float scv0 = psum0 * SCALE, scv1 = psum1 * SCALE;                         \
    P0 = (row0 <= pos_tk)      ? scv0 * fast_sigmoid(scv0) * 16.f : 0.f;      \
    P1 = (row0 + 16 <= pos_tk) ? scv1 * fast_sigmoid(scv1) * 16.f : 0.f;      \
} while (0)

// Kernel 3a (R18): slc gather; 3-way token interleave in the want loop.
// R17 post-mortem: slc pinned at ~80us across 3 structurally different
// memory plans -> the binding constraint is the SERIAL want-loop chain
// (q-LDS-read ~120cy -> 32-FMA dot -> 2 shuffles -> sigmoid -> 16-deep
// readlane PV -> LDS atomic ~= 1.5-2Kcy x ~15 serial iters/wave = measured
// 28us wave lifetime; 1.9 waves/SIMD can't hide it). R18: process up to 3
// tokens per iteration (independent chains, uniform branches) and SHARE the
// 32 V LDS reads across them (LDS issue per token /3). Memory plan unchanged.
__global__ __launch_bounds__(256) void slc_kernel(
    const float* __restrict__ q, const float* __restrict__ k,
    const float* __restrict__ v,
    const int* __restrict__ x_offsets, const int* __restrict__ batch_ids,
    const int* __restrict__ pos_ids,
    const int2* __restrict__ idxbuf, float* __restrict__ os_out, int T) {
    int i  = blockIdx.x;
    int wg = (i & 7) * (gridDim.x >> 3) + (i >> 3);  // XCD chunks (grid %8==0)
    int qb = wg >> 2;             // q-block index (32 tokens)
    int h  = wg & 3;              // head
    int t0 = qb * 32;
    int tid  = threadIdx.x;
    int wv   = __builtin_amdgcn_readfirstlane(tid >> 6);
    int lane = tid & 63;

    int b    = batch_ids[t0];
    int pos0 = pos_ids[t0];       // q-blocks never straddle seqs (lengths %256==0)
    int s0   = x_offsets[b];
    int qblk = pos0 >> 5;         // uniform across the 32 tokens

    __shared__ float q_lds[32 * 68];     // [tk][68] padded q rows, 8704 B
    __shared__ float os_lds[32 * 64];    // [tk][d] o_slc accumulator, 8192 B
    __shared__ float vs_lds[4 * 32 * 64];// per-wave V block [32 rows][64 d], 32768 B
    float* vs_w = vs_lds + wv * 2048;

    // stage q head-slice: 512 float4 over 256 threads
    const float4* q4 = (const float4*)(q + (size_t)t0 * HIDDEN + h * HD);
    #pragma unroll
    for (int rep = 0; rep < 2; ++rep) {
        int f4i = tid + 256 * rep;
        int tk = f4i >> 4, c4 = f4i & 15;
        *(float4*)(&q_lds[tk * 68 + c4 * 4]) = q4[(size_t)tk * 64 + c4];
    }
    #pragma unroll
    for (int rep = 0; rep < 8; ++rep) os_lds[tid + 256 * rep] = 0.f;

    // per-token selections at lanes 0..31 (each wave loads its own copy);
    // invalid B-slot (idx2>qblk) dropped
    int myi0 = -1, myi2 = -1;
    unsigned long long U = 0ull;
    if (lane < 32) {
        int2 ix = idxbuf[(size_t)(t0 + lane) * NH + h];
        myi0 = ix.x;
        myi2 = (ix.y <= qblk) ? ix.y : -1;
        U = (1ull << myi0);
        if (myi2 >= 0) U |= (1ull << myi2);
    }
    #pragma unroll
    for (int off = 1; off < 64; off <<= 1) U |= __shfl_xor(U, off, 64);
    __syncthreads();

    int r  = lane & 15, cc = lane >> 4;
    const float* kbase = k + (size_t)s0 * HIDDEN + h * HD;
    const float* vbase = v + (size_t)s0 * HIDDEN + h * HD + lane;

    int cnt = 0;
    while (U) {
        int m = (int)__builtin_ctzll(U); U &= U - 1;
        if (((cnt++) & 3) != wv) continue;          // rank round-robin partition
        // gather K block m: lane (r,cc) holds rows {r, 16+r}, 16-float strip
        const float* kb_p = kbase + (size_t)(m * BS) * HIDDEN;
        float4 kb0[4], kb1[4];
        #pragma unroll
        for (int j = 0; j < 4; ++j) {
            kb0[j] = *(const float4*)(kb_p + (size_t)r * HIDDEN + (cc + 4 * j) * 4);
            kb1[j] = *(const float4*)(kb_p + (size_t)(16 + r) * HIDDEN + (cc + 4 * j) * 4);
        }
        // stage V block m into this wave's LDS buffer: groups of 8 named
        // scalars (registers, rule #20) -> 8 loads in flight, 8 ds_writes.
        {
            const float* vb_p = vbase + (size_t)(m * BS) * HIDDEN;
            #pragma unroll
            for (int g = 0; g < 4; ++g) {
                const float* p0_ = vb_p + (size_t)(g * 8) * HIDDEN;
                float x0 = p0_[0 * HIDDEN], x1 = p0_[1 * HIDDEN];
                float x2 = p0_[2 * HIDDEN], x3 = p0_[3 * HIDDEN];
                float x4 = p0_[4 * HIDDEN], x5 = p0_[5 * HIDDEN];
                float x6 = p0_[6 * HIDDEN], x7 = p0_[7 * HIDDEN];
                float* d0 = vs_w + (g * 8) * 64 + lane;
                d0[0 * 64] = x0; d0[1 * 64] = x1; d0[2 * 64] = x2; d0[3 * 64] = x3;
                d0[4 * 64] = x4; d0[5 * 64] = x5; d0[6 * 64] = x6; d0[7 * 64] = x7;
            }
        }
        // pin K block in VGPRs (R15 failure mode: loads sunk into token loop)
        #pragma unroll
        for (int j = 0; j < 4; ++j) {
            asm volatile("" : "+v"(kb0[j].x), "+v"(kb0[j].y),
                              "+v"(kb0[j].z), "+v"(kb0[j].w));
            asm volatile("" : "+v"(kb1[j].x), "+v"(kb1[j].y),
                              "+v"(kb1[j].z), "+v"(kb1[j].w));
        }
        int row0 = m * BS + r;

        unsigned long long want =
            __ballot(lane < 32 && (myi0 == m || myi2 == m));
        while (want) {
            // pull up to 3 tokens (want is wave-uniform -> uniform branches)
            int tk0 = (int)__builtin_ctzll(want); want &= want - 1;
            int tk1 = -1, tk2 = -1;
            if (want) { tk1 = (int)__builtin_ctzll(want); want &= want - 1; }
            if (want) { tk2 = (int)__builtin_ctzll(want); want &= want - 1; }

            float pa0 = 0.f, pa1 = 0.f, pb0 = 0.f, pb1 = 0.f, pc0 = 0.f, pc1 = 0.f;
            SCORE_TOK(tk0, pa0, pa1);
            if (tk1 >= 0) SCORE_TOK(tk1, pb0, pb1);
            if (tk2 >= 0) SCORE_TOK(tk2, pc0, pc1);

            // fused PV: V reads shared across the 3 tokens; 6 independent
            // 16-deep FMA chains (invalid tokens contribute with p==0).
            float oA0 = 0.f, oA1 = 0.f, oB0 = 0.f, oB1 = 0.f, oC0 = 0.f, oC1 = 0.f;
            #pragma unroll
            for (int rr = 0; rr < 16; ++rr) {
                float v0 = vs_w[rr * 64 + lane];
                float v1 = vs_w[(16 + rr) * 64 + lane];
                oA0 += readlane_f(pa0, rr) * v0;  oA1 += readlane_f(pa1, rr) * v1;
                oB0 += readlane_f(pb0, rr) * v0;  oB1 += readlane_f(pb1, rr) * v1;
                oC0 += readlane_f(pc0, rr) * v0;  oC1 += readlane_f(pc1, rr) * v1;
            }
            atomicAdd(&os_lds[tk0 * 64 + lane], oA0 + oA1);
            if (tk1 >= 0) atomicAdd(&os_lds[tk1 * 64 + lane], oB0 + oB1);
            if (tk2 >= 0) atomicAdd(&os_lds[tk2 * 64 + lane], oC0 + oC1);
        }
    }
    __syncthreads();

    // write o_slc (pre-LN) to os_out (= d_out, consumed+overwritten by ln_kernel)
    float* ob = os_out + (size_t)t0 * HIDDEN + h * HD;
    #pragma unroll
    for (int rep = 0; rep < 8; ++rep) {
        int idx = tid + 256 * rep;
        int tk = idx >> 6, d = idx & 63;
        ob[(size_t)tk * HIDDEN + d] = os_lds[idx];
    }
}

// Kernel 3b: gate + dual LayerNorm, streaming. WG = 8 tokens x 32 lanes
// (8 dims each). Reads oc_buf (raw o_cmp) and d_out (raw o_slc), writes final.
__global__ __launch_bounds__(256) void ln_kernel(
    const float* __restrict__ q, const float* __restrict__ u,
    const float* __restrict__ Wg_cmp,
    const float* __restrict__ oc_buf, float* __restrict__ io, int T) {
    int tid = threadIdx.x;
    int grp = tid >> 5;           // token within group of 8
    int sub = tid & 31;           // dim strip
    int t   = blockIdx.x * 8 + grp;
    int D0  = sub * 8;            // 8 dims per lane (all within one head)

    const float4* qp = (const float4*)(q + (size_t)t * HIDDEN + D0);
    float4 qa = qp[0], qb = qp[1];
    const float4* wp = (const float4*)(Wg_cmp + D0);   // [NH][64] flat = [256]
    float4 wa = wp[0], wb = wp[1];
    float gp = qa.x * wa.x + qa.y * wa.y + qa.z * wa.z + qa.w * wa.w
             + qb.x * wb.x + qb.y * wb.y + qb.z * wb.z + qb.w * wb.w;
    gp += __shfl_xor(gp, 1, 64);
    gp += __shfl_xor(gp, 2, 64);
    gp += __shfl_xor(gp, 4, 64);   // sum over the head's 8 lanes
    float g = fast_sigmoid(gp);

    const float4* ocp = (const float4*)(oc_buf + (size_t)t * HIDDEN + D0);
    float4 oa = ocp[0], ob = ocp[1];
    oa.x *= g; oa.y *= g; oa.z *= g; oa.w *= g;
    ob.x *= g; ob.y *= g; ob.z *= g; ob.w *= g;
    float4* iop = (float4*)(io + (size_t)t * HIDDEN + D0);
    float4 sa = iop[0], sb = iop[1];

    float sc_ = oa.x + oa.y + oa.z + oa.w + ob.x + ob.y + ob.z + ob.w;
    float sc2 = oa.x * oa.x + oa.y * oa.y + oa.z * oa.z + oa.w * oa.w
              + ob.x * ob.x + ob.y * ob.y + ob.z * ob.z + ob.w * ob.w;
    float ss_ = sa.x + sa.y + sa.z + sa.w + sb.x + sb.y + sb.z + sb.w;
    float ss2 = sa.x * sa.x + sa.y * sa.y + sa.z * sa.z + sa.w * sa.w
              + sb.x * sb.x + sb.y * sb.y + sb.z * sb.z + sb.w * sb.w;
    #pragma unroll
    for (int off = 1; off < 32; off <<= 1) {
        sc_ += __shfl_xor(sc_, off, 64);
        sc2 += __shfl_xor(sc2, off, 64);
        ss_ += __shfl_xor(ss_, off, 64);
        ss2 += __shfl_xor(ss2, off, 64);
    }
    float muc  = sc_ * (1.0f / HIDDEN);
    float varc = sc2 * (1.0f / HIDDEN) - muc * muc;
    float mus  = ss_ * (1.0f / HIDDEN);
    float vars = ss2 * (1.0f / HIDDEN) - mus * mus;
    float rc = rsqrtf(varc + 1e-6f), rs = rsqrtf(vars + 1e-6f);

    const float4* up = (const float4*)(u + (size_t)t * HIDDEN + D0);
    float4 ua = up[0], ub = up[1];
    float4 o0, o1;
    o0.x = ((oa.x - muc) * rc + (sa.x - mus) * rs) * ua.x;
    o0.y = ((oa.y - muc) * rc + (sa.y - mus) * rs) * ua.y;
    o0.z = ((oa.z - muc) * rc + (sa.z - mus) * rs) * ua.z;
    o0.w = ((oa.w - muc) * rc + (sa.w - mus) * rs) * ua.w;
    o1.x = ((ob.x - muc) * rc + (sb.x - mus) * rs) * ub.x;
    o1.y = ((ob.y - muc) * rc + (sb.y - mus) * rs) * ub.y;
    o1.z = ((ob.z - muc) * rc + (sb.z - mus) * rs) * ub.z;
    o1.w = ((ob.w - muc) * rc + (sb.w - mus) * rs) * ub.w;
    iop[0] = o0; iop[1] = o1;
}

extern "C" void kernel_launch(void* const* d_in, const int* in_sizes, int n_in,
                              void* d_out, int out_size, void* d_ws, size_t ws_size,
                              hipStream_t stream) {
    const float* q      = (const float*)d_in[0];
    const float* k      = (const float*)d_in[1];
    const float* v      = (const float*)d_in[2];
    const float* u      = (const float*)d_in[3];
    const float* Wg_cmp = (const float*)d_in[4];
    // d_in[5] = Wg_slc: dead code in the reference (computed, never used)
    const int* x_offsets = (const int*)d_in[6];
    const int* batch_ids = (const int*)d_in[7];
    const int* pos_ids   = (const int*)d_in[8];

    int T = in_sizes[0] / HIDDEN;   // 11008; all lengths are multiples of 256
    int B = in_sizes[6] - 1;

    double* k_cmp  = (double*)d_ws;                                 // B*NH*4096 doubles
    float*  v_cmp2 = (float*)(k_cmp + (size_t)B * NH * 4096);       // B*NH*4096 floats
    float*  oc_buf = v_cmp2 + (size_t)B * NH * 4096;                // T*256 floats
    int2*   idxbuf = (int2*)(oc_buf + (size_t)T * HIDDEN);          // T*NH int2

    kcmp_kernel<<<dim3(B * NB, 2), 256, 0, stream>>>(k, v, x_offsets, k_cmp, v_cmp2);
    cmp_kernel<<<dim3(T / 64, NH), 256, 0, stream>>>(
        q, batch_ids, pos_ids, k_cmp, v_cmp2, oc_buf, idxbuf, T);
    // 3a: o_slc (pre-LN) staged into d_out; 3b: gate + LN overwrite d_out
    slc_kernel<<<dim3((T / 32) * NH), 256, 0, stream>>>(
        q, k, v, x_offsets, batch_ids, pos_ids, idxbuf, (float*)d_out, T);
    ln_kernel<<<dim3(T / 8), 256, 0, stream>>>(
        q, u, Wg_cmp, oc_buf, (float*)d_out, T);
}